// Round 6
// baseline (2176.280 us; speedup 1.0000x reference)
//
#include <hip/hip_runtime.h>
#include <hip/hip_bf16.h>
#include <math.h>

#define N_NODES 200000
#define T_TREES 2000
#define S_NODES 100
#define F_DIM 256
#define H_DIM 256
#define G_DIM 768   // 3*H
#define D_MAX 28    // upper bound on depth layers (actual ~16; empties exit fast)

typedef __attribute__((ext_vector_type(8))) short short8b;   // 8 bf16 = 4 VGPR
typedef __attribute__((ext_vector_type(4))) float f32x4;

// HW-converted RNE cast (compiler emits v_cvt)
static __device__ __forceinline__ unsigned short f2bf(float x) {
    union { __hip_bfloat16 h; unsigned short u; } cv;
    cv.h = __float2bfloat16(x);
    return cv.u;
}
static __device__ __forceinline__ float bf2f(unsigned short u) {
    return __uint_as_float(((unsigned)u) << 16);
}

// ---------------------------------------------------------------------------
__global__ void k_zero(float4* __restrict__ p, int n4) {
    float4 z = make_float4(0.f, 0.f, 0.f, 0.f);
    for (int i = blockIdx.x * blockDim.x + threadIdx.x; i < n4;
         i += gridDim.x * blockDim.x)
        p[i] = z;
}

// M = min{ p >= T : layer_nodes[p] < N } (layer 0 is exactly the T roots)
__global__ void k_findM(const int* __restrict__ ln, int LM, int* __restrict__ Mdev) {
    int local = 0x7F7F7F7F;
    for (int p = T_TREES + blockIdx.x * blockDim.x + threadIdx.x; p < LM;
         p += gridDim.x * blockDim.x)
        if (ln[p] < N_NODES && p < local) local = p;
#pragma unroll
    for (int off = 32; off; off >>= 1) {
        int o = __shfl_down(local, off);
        if (o < local) local = o;
    }
    __shared__ int wmin[4];
    if ((threadIdx.x & 63) == 0) wmin[threadIdx.x >> 6] = local;
    __syncthreads();
    if (threadIdx.x == 0) {
        int m = wmin[0];
        for (int i = 1; i < 4; ++i) if (wmin[i] < m) m = wmin[i];
        if (m < 0x7F7F7F7F) atomicMin(Mdev, m);
    }
}

// layer_cnt[d] = #valid nodes in layer d (valid entries are a row prefix)
__global__ void k_hist(const int* __restrict__ ln, const int* __restrict__ Mdev,
                       int* __restrict__ layer_cnt, int LM) {
    __shared__ int h[D_MAX];
    if (threadIdx.x < D_MAX) h[threadIdx.x] = 0;
    __syncthreads();
    const int M = Mdev[0];
    for (int p = blockIdx.x * blockDim.x + threadIdx.x; p < LM;
         p += gridDim.x * blockDim.x)
        if (ln[p] < N_NODES) {
            int d = p / M;
            if (d < D_MAX) atomicAdd(&h[d], 1);
        }
    __syncthreads();
    if (threadIdx.x < D_MAX && h[threadIdx.x])
        atomicAdd(&layer_cnt[threadIdx.x], h[threadIdx.x]);
}

// parent[kid] = node, cnt[node] = #children (layout-free flat scan)
__global__ void k_build(const int* __restrict__ layer_nodes,
                        const int* __restrict__ child_idx,
                        const int* __restrict__ child_cnt,
                        int* __restrict__ parent,
                        int* __restrict__ cnt,
                        int LM, int C) {
    for (int p = blockIdx.x * blockDim.x + threadIdx.x; p < LM;
         p += gridDim.x * blockDim.x) {
        int node = layer_nodes[p];
        if (node < N_NODES) {
            cnt[node] = child_cnt[p];
            const int* ch = child_idx + (size_t)p * C;
            for (int c = 0; c < C; ++c) {
                int k = ch[c];
                if (k < N_NODES) parent[k] = node;
            }
        }
    }
}

// Weights fp32 -> bf16 (row-major [g][k])
__global__ void k_convw(const float* __restrict__ wi, const float* __restrict__ wh,
                        unsigned short* __restrict__ wib, unsigned short* __restrict__ whb) {
    int i = blockIdx.x * blockDim.x + threadIdx.x;
    if (i < G_DIM * F_DIM) {
        wib[i] = f2bf(wi[i]);
        whb[i] = f2bf(wh[i]);
    }
}

// ---------------------------------------------------------------------------
// One-shot GEMM: gi_all[m][g] = (sum_k x[m][k] * w_ih[g][k]) + b_ih[g]  (bf16)
// No LDS, no barriers: B fragments straight from L2. Slot-permuted B so each
// lane owns 8 contiguous g -> one 16B store. Wave tile 32m x 64g per (nt,nsp).
// ---------------------------------------------------------------------------
__global__ __launch_bounds__(256) void k_gemm_x(
    const float* __restrict__ x,
    const unsigned short* __restrict__ wib,
    const float* __restrict__ b_ih,
    unsigned short* __restrict__ gi_all) {
    const int tid = threadIdx.x;
    const int wv = tid >> 6, lane = tid & 63;
    const int lr = lane & 15, kg = lane >> 4;
    const long m0 = (long)blockIdx.x * 128 + wv * 32;

    // A fragments: fp32 -> bf16 once, reused for all 24 output tiles
    short8b A[2][8];
#pragma unroll
    for (int ms = 0; ms < 2; ++ms) {
        long r = m0 + ms * 16 + lr;
        if (r > N_NODES - 1) r = N_NODES - 1;
        const float* xp = x + r * F_DIM + kg * 8;
#pragma unroll
        for (int ks = 0; ks < 8; ++ks) {
            float4 u = *(const float4*)(xp + ks * 32);
            float4 v = *(const float4*)(xp + ks * 32 + 4);
            short8b t;
            t[0] = f2bf(u.x); t[1] = f2bf(u.y); t[2] = f2bf(u.z); t[3] = f2bf(u.w);
            t[4] = f2bf(v.x); t[5] = f2bf(v.y); t[6] = f2bf(v.z); t[7] = f2bf(v.w);
            A[ms][ks] = t;
        }
    }

    // permuted slot->row offset: slot s holds g = base + (s>>2)*8 + (s&3)
    const int gp_off = (lr >> 2) * 8 + (lr & 3);
    const f32x4 zf = {0.f, 0.f, 0.f, 0.f};

    for (int nt = 0; nt < 12; ++nt) {
#pragma unroll
        for (int nsp = 0; nsp < 2; ++nsp) {
            const int base_g = nt * 64 + nsp * 32;
            f32x4 accP[2], accQ[2];
#pragma unroll
            for (int ms = 0; ms < 2; ++ms) { accP[ms] = zf; accQ[ms] = zf; }

            const unsigned short* bp =
                wib + (size_t)(base_g + gp_off) * F_DIM + kg * 8;
#pragma unroll
            for (int ks = 0; ks < 8; ++ks) {
                short8b BP = *(const short8b*)(bp + ks * 32);
                short8b BQ = *(const short8b*)(bp + 4 * F_DIM + ks * 32);
#pragma unroll
                for (int ms = 0; ms < 2; ++ms) {
                    accP[ms] = __builtin_amdgcn_mfma_f32_16x16x32_bf16(
                        BP, A[ms][ks], accP[ms], 0, 0, 0);
                    accQ[ms] = __builtin_amdgcn_mfma_f32_16x16x32_bf16(
                        BQ, A[ms][ks], accQ[ms], 0, 0, 0);
                }
            }

            const int g0 = base_g + kg * 8;   // lane's 8 contiguous gates
            f32x4 b0 = *(const f32x4*)(b_ih + g0);
            f32x4 b1 = *(const f32x4*)(b_ih + g0 + 4);
#pragma unroll
            for (int ms = 0; ms < 2; ++ms) {
                long m = m0 + ms * 16 + lr;
                if (m < N_NODES) {
                    short8b pk;
#pragma unroll
                    for (int i = 0; i < 4; ++i) {
                        pk[i]     = f2bf(accP[ms][i] + b0[i]);
                        pk[4 + i] = f2bf(accQ[ms][i] + b1[i]);
                    }
                    *(short8b*)(gi_all + m * G_DIM + g0) = pk;
                }
            }
        }
    }
}

// ---------------------------------------------------------------------------
// One depth layer, SCATTER version: h_prev for node = hsum[node]*inv (one
// coalesced fp32 row read; children already accumulated by the previous,
// deeper launch). Epilogue atomicAdds finished h into hsum[parent].
// Tile = 32 nodes; 4 waves split 768 gate cols; 2 MFMA per B-load.
// ---------------------------------------------------------------------------
__global__ __launch_bounds__(256) void k_layer(
    const int* __restrict__ layer_nodes,
    const int* __restrict__ Mdev,
    const int* __restrict__ layer_cnt,
    const int* __restrict__ cnt,
    const int* __restrict__ parent,
    const unsigned short* __restrict__ whb,
    const unsigned short* __restrict__ gi_all,
    const float* __restrict__ b_hh,
    float* __restrict__ hsum,
    float* __restrict__ out,
    int d) {
    __shared__ unsigned short Ab[32][274];  // h_prev bf16 (odd-dword pad)
    __shared__ int Nd[32];
    __shared__ float Iv[32];
    __shared__ int Pp[32];

    const int cntd = layer_cnt[d];
    if (cntd == 0) return;
    const int M = Mdev[0];
    const int ntiles = (cntd + 31) >> 5;
    const long pbase = (long)d * M;

    const int tid = threadIdx.x;
    const int wv = tid >> 6, lane = tid & 63;
    const int lr = lane & 15, kg = lane >> 4;
    const int cb = wv * 64;

    float bh[3][4];
#pragma unroll
    for (int c = 0; c < 3; ++c)
#pragma unroll
        for (int ns = 0; ns < 4; ++ns)
            bh[c][ns] = b_hh[c * 256 + cb + ns * 16 + lr];

    const int srow = tid >> 3;      // 0..31 staging row (8 threads/row)
    const int sc8 = tid & 7;        // 32 contiguous floats per thread

    for (int tile = blockIdx.x; tile < ntiles; tile += gridDim.x) {
        __syncthreads();   // previous tile's LDS reads done
        // ---- stage h_prev = hsum[node]*inv into bf16 LDS ----
        {
            int idx = tile * 32 + srow;
            int node = (idx < cntd) ? layer_nodes[pbase + idx] : -1;
            float inv = 0.f;
            if (node >= 0) {
                int c = cnt[node];
                inv = 1.0f / (float)(c > 0 ? c : 1);
            }
            if (sc8 == 0) {
                Nd[srow] = node;
                Iv[srow] = inv;
                Pp[srow] = (node >= 0 && d > 0) ? parent[node] : 0;
            }
            const float* hr = hsum + (size_t)(node >= 0 ? node : 0) * H_DIM + sc8 * 32;
#pragma unroll
            for (int q = 0; q < 4; ++q) {
                float4 u = make_float4(0.f, 0.f, 0.f, 0.f), v = u;
                if (node >= 0) {
                    u = *(const float4*)(hr + q * 8);
                    v = *(const float4*)(hr + q * 8 + 4);
                }
                short8b pk;
                pk[0] = f2bf(u.x * inv); pk[1] = f2bf(u.y * inv);
                pk[2] = f2bf(u.z * inv); pk[3] = f2bf(u.w * inv);
                pk[4] = f2bf(v.x * inv); pk[5] = f2bf(v.y * inv);
                pk[6] = f2bf(v.z * inv); pk[7] = f2bf(v.w * inv);
                *(short8b*)&Ab[srow][sc8 * 32 + q * 8] = pk;
            }
        }
        __syncthreads();

        // ---- A fragments from LDS (2 m-subtiles) ----
        short8b A[2][8];
#pragma unroll
        for (int ms = 0; ms < 2; ++ms)
#pragma unroll
            for (int ks = 0; ks < 8; ++ks)
                A[ms][ks] = *(const short8b*)&Ab[ms * 16 + lr][ks * 32 + kg * 8];

        // ---- GEMM: acc[c][ms][ns] = h_prev @ w_hh^T ----
        const f32x4 zf = {0.f, 0.f, 0.f, 0.f};
        f32x4 acc[3][2][4];
#pragma unroll
        for (int c = 0; c < 3; ++c)
#pragma unroll
            for (int ms = 0; ms < 2; ++ms)
#pragma unroll
                for (int ns = 0; ns < 4; ++ns) acc[c][ms][ns] = zf;

#pragma unroll
        for (int ks = 0; ks < 8; ++ks)
#pragma unroll
            for (int c = 0; c < 3; ++c)
#pragma unroll
                for (int ns = 0; ns < 4; ++ns) {
                    short8b B = *(const short8b*)(whb
                        + (size_t)(c * 256 + cb + ns * 16 + lr) * H_DIM
                        + ks * 32 + kg * 8);
#pragma unroll
                    for (int ms = 0; ms < 2; ++ms)
                        acc[c][ms][ns] = __builtin_amdgcn_mfma_f32_16x16x32_bf16(
                            A[ms][ks], B, acc[c][ms][ns], 0, 0, 0);
                }

        // ---- fused GRU epilogue + scatter to parent ----
#pragma unroll
        for (int ms = 0; ms < 2; ++ms) {
            int nds[4], prs[4];
            float ivs[4];
            unsigned short g_r[4][4], g_z[4][4], g_n[4][4];
#pragma unroll
            for (int i = 0; i < 4; ++i) {
                int rl = ms * 16 + kg * 4 + i;
                int nd = Nd[rl];
                nds[i] = nd; ivs[i] = Iv[rl]; prs[i] = Pp[rl];
                if (nd >= 0) {
                    const unsigned short* gp = gi_all + (size_t)nd * G_DIM;
#pragma unroll
                    for (int ns = 0; ns < 4; ++ns) {
                        int k = cb + ns * 16 + lr;
                        g_r[i][ns] = gp[k];
                        g_z[i][ns] = gp[256 + k];
                        g_n[i][ns] = gp[512 + k];
                    }
                }
            }
#pragma unroll
            for (int ns = 0; ns < 4; ++ns) {
                int k = cb + ns * 16 + lr;
#pragma unroll
                for (int i = 0; i < 4; ++i) {
                    int nd = nds[i];
                    if (nd < 0) continue;
                    float hp = hsum[(size_t)nd * H_DIM + k] * ivs[i];
                    float xr = bf2f(g_r[i][ns]) + acc[0][ms][ns][i] + bh[0][ns];
                    float xz = bf2f(g_z[i][ns]) + acc[1][ms][ns][i] + bh[1][ns];
                    float r = 1.0f / (1.0f + expf(-xr));
                    float z = 1.0f / (1.0f + expf(-xz));
                    float n = tanhf(bf2f(g_n[i][ns]) + r * (acc[2][ms][ns][i] + bh[2][ns]));
                    float h = (1.0f - z) * n + z * hp;
                    if (d == 0) {
                        out[(size_t)(nd / S_NODES) * H_DIM + k] = h;
                    } else {
                        atomicAdd(&hsum[(size_t)prs[i] * H_DIM + k], h);
                    }
                }
            }
        }
    }
}

// ---------------------------------------------------------------------------
extern "C" void kernel_launch(void* const* d_in, const int* in_sizes, int n_in,
                              void* d_out, int out_size, void* d_ws, size_t ws_size,
                              hipStream_t stream) {
    const float* inputs = (const float*)d_in[0];
    const float* w_ih   = (const float*)d_in[1];
    const float* w_hh   = (const float*)d_in[2];
    const float* b_ih   = (const float*)d_in[3];
    const float* b_hh   = (const float*)d_in[4];
    const int* layer_nodes = (const int*)d_in[5];
    const int* child_idx   = (const int*)d_in[6];
    const int* child_cnt   = (const int*)d_in[7];

    const int LM = in_sizes[5];
    const int C  = in_sizes[6] / in_sizes[5];

    char* w = (char*)d_ws;
    size_t o = 0;
    auto alloc = [&](size_t bytes) {
        void* p = w + o;
        o += (bytes + 255) & ~(size_t)255;
        return p;
    };
    int*            parent = (int*)alloc((size_t)N_NODES * 4);
    int*            cnt    = (int*)alloc((size_t)N_NODES * 4);
    unsigned short* wib    = (unsigned short*)alloc((size_t)G_DIM * F_DIM * 2);
    unsigned short* whb    = (unsigned short*)alloc((size_t)G_DIM * H_DIM * 2);
    float*          hsum   = (float*)alloc((size_t)N_NODES * H_DIM * 4);
    unsigned short* gi_all = (unsigned short*)alloc((size_t)N_NODES * G_DIM * 2);
    int*            Mdev      = (int*)alloc(4);
    int*            layer_cnt = (int*)alloc(D_MAX * 4);
    (void)ws_size;

    hipMemsetAsync(Mdev, 0x7F, 4, stream);                 // 0x7F7F7F7F > LM
    hipMemsetAsync(layer_cnt, 0, D_MAX * 4, stream);

    k_zero<<<2048, 256, 0, stream>>>((float4*)hsum, N_NODES * H_DIM / 4);
    k_findM<<<256, 256, 0, stream>>>(layer_nodes, LM, Mdev);
    k_hist<<<256, 256, 0, stream>>>(layer_nodes, Mdev, layer_cnt, LM);
    k_build<<<256, 256, 0, stream>>>(layer_nodes, child_idx, child_cnt,
                                     parent, cnt, LM, C);
    k_convw<<<(G_DIM * F_DIM + 255) / 256, 256, 0, stream>>>(w_ih, w_hh, wib, whb);

    // One-shot feed-forward GEMM (b_ih folded in), barrier-free
    k_gemm_x<<<(N_NODES + 127) / 128, 256, 0, stream>>>(inputs, wib, b_ih, gi_all);

    // Depth layers, deepest first (empty layers exit immediately)
    for (int d = D_MAX - 1; d >= 0; --d)
        k_layer<<<512, 256, 0, stream>>>(layer_nodes, Mdev, layer_cnt, cnt,
                                         parent, whb, gi_all, b_hh,
                                         hsum, (float*)d_out, d);
}

// Round 7
// 1342.479 us; speedup vs baseline: 1.6211x; 1.6211x over previous
//
#include <hip/hip_runtime.h>
#include <hip/hip_bf16.h>
#include <math.h>

#define N_NODES 200000
#define T_TREES 2000
#define S_NODES 100
#define F_DIM 256
#define H_DIM 256
#define G_DIM 768   // 3*H
#define D_MAX 28    // upper bound on depth layers (actual ~16)

typedef __attribute__((ext_vector_type(8))) short short8b;   // 8 bf16 = 4 VGPR
typedef __attribute__((ext_vector_type(4))) float f32x4;

static __device__ __forceinline__ unsigned short f2bf(float x) {
    union { __hip_bfloat16 h; unsigned short u; } cv;
    cv.h = __float2bfloat16(x);
    return cv.u;
}
static __device__ __forceinline__ float bf2f(unsigned short u) {
    return __uint_as_float(((unsigned)u) << 16);
}

// ---------------------------------------------------------------------------
__global__ void k_zero(float4* __restrict__ p, int n4) {
    float4 z = make_float4(0.f, 0.f, 0.f, 0.f);
    for (int i = blockIdx.x * blockDim.x + threadIdx.x; i < n4;
         i += gridDim.x * blockDim.x)
        p[i] = z;
}

// x (fp32) -> bf16, 8 elems/thread
__global__ void k_convx(const float* __restrict__ x, unsigned short* __restrict__ xb,
                        int n8) {
    for (int i = blockIdx.x * blockDim.x + threadIdx.x; i < n8;
         i += gridDim.x * blockDim.x) {
        const float4* px = (const float4*)(x + (size_t)i * 8);
        float4 u = px[0], v = px[1];
        short8b t;
        t[0] = f2bf(u.x); t[1] = f2bf(u.y); t[2] = f2bf(u.z); t[3] = f2bf(u.w);
        t[4] = f2bf(v.x); t[5] = f2bf(v.y); t[6] = f2bf(v.z); t[7] = f2bf(v.w);
        *(short8b*)(xb + (size_t)i * 8) = t;
    }
}

// M = min{ p >= T : layer_nodes[p] < N } (layer 0 is exactly the T roots)
__global__ void k_findM(const int* __restrict__ ln, int LM, int* __restrict__ Mdev) {
    int local = 0x7F7F7F7F;
    for (int p = T_TREES + blockIdx.x * blockDim.x + threadIdx.x; p < LM;
         p += gridDim.x * blockDim.x)
        if (ln[p] < N_NODES && p < local) local = p;
#pragma unroll
    for (int off = 32; off; off >>= 1) {
        int o = __shfl_down(local, off);
        if (o < local) local = o;
    }
    __shared__ int wmin[4];
    if ((threadIdx.x & 63) == 0) wmin[threadIdx.x >> 6] = local;
    __syncthreads();
    if (threadIdx.x == 0) {
        int m = wmin[0];
        for (int i = 1; i < 4; ++i) if (wmin[i] < m) m = wmin[i];
        if (m < 0x7F7F7F7F) atomicMin(Mdev, m);
    }
}

// layer_cnt[d] = #valid nodes in layer d (valid entries are a row prefix)
__global__ void k_hist(const int* __restrict__ ln, const int* __restrict__ Mdev,
                       int* __restrict__ layer_cnt, int LM) {
    __shared__ int h[D_MAX];
    if (threadIdx.x < D_MAX) h[threadIdx.x] = 0;
    __syncthreads();
    const int M = Mdev[0];
    for (int p = blockIdx.x * blockDim.x + threadIdx.x; p < LM;
         p += gridDim.x * blockDim.x)
        if (ln[p] < N_NODES) {
            int d = p / M;
            if (d < D_MAX) atomicAdd(&h[d], 1);
        }
    __syncthreads();
    if (threadIdx.x < D_MAX && h[threadIdx.x])
        atomicAdd(&layer_cnt[threadIdx.x], h[threadIdx.x]);
}

// Weights fp32 -> bf16 (row-major [g][k])
__global__ void k_convw(const float* __restrict__ wi, const float* __restrict__ wh,
                        unsigned short* __restrict__ wib, unsigned short* __restrict__ whb) {
    int i = blockIdx.x * blockDim.x + threadIdx.x;
    if (i < G_DIM * F_DIM) {
        wib[i] = f2bf(wi[i]);
        whb[i] = f2bf(wh[i]);
    }
}

// ---------------------------------------------------------------------------
// One-shot GEMM: gi_all[m][g] = (sum_k xb[m][k] * w_ih[g][k]) + b_ih[g]  (bf16)
// No LDS, no barriers. B fragments explicitly DOUBLE-BUFFERED in registers:
// tile p+1's 16 loads issue before tile p's 32 MFMAs -> 16KB/wave in flight.
// Slot-permuted B rows so each lane owns 8 contiguous g -> one 16B store.
// ---------------------------------------------------------------------------
#define LOADB(Bdst, p_)                                                         \
  {                                                                             \
    const unsigned short* bp_ =                                                 \
        wib + (size_t)((p_) * 32 + gp_off) * F_DIM + kg * 8;                    \
    _Pragma("unroll")                                                           \
    for (int ks = 0; ks < 8; ++ks) {                                            \
      Bdst[ks]     = *(const short8b*)(bp_ + ks * 32);                          \
      Bdst[8 + ks] = *(const short8b*)(bp_ + 4 * F_DIM + ks * 32);              \
    }                                                                           \
  }

#define GXSTEP(Bcur, Bnxt, p_)                                                  \
  {                                                                             \
    if ((p_) + 1 < 24) LOADB(Bnxt, (p_) + 1);                                   \
    f32x4 aP0 = zf, aP1 = zf, aQ0 = zf, aQ1 = zf;                               \
    _Pragma("unroll")                                                           \
    for (int ks = 0; ks < 8; ++ks) {                                            \
      aP0 = __builtin_amdgcn_mfma_f32_16x16x32_bf16(Bcur[ks], A[0][ks], aP0, 0, 0, 0);     \
      aQ0 = __builtin_amdgcn_mfma_f32_16x16x32_bf16(Bcur[8 + ks], A[0][ks], aQ0, 0, 0, 0); \
      aP1 = __builtin_amdgcn_mfma_f32_16x16x32_bf16(Bcur[ks], A[1][ks], aP1, 0, 0, 0);     \
      aQ1 = __builtin_amdgcn_mfma_f32_16x16x32_bf16(Bcur[8 + ks], A[1][ks], aQ1, 0, 0, 0); \
    }                                                                           \
    const int g0 = (p_) * 32 + kg * 8;                                          \
    f32x4 b0 = *(const f32x4*)(b_ih + g0);                                      \
    f32x4 b1 = *(const f32x4*)(b_ih + g0 + 4);                                  \
    {                                                                           \
      long m = m0 + lr;                                                         \
      if (m < N_NODES) {                                                        \
        short8b pk;                                                             \
        _Pragma("unroll")                                                       \
        for (int i = 0; i < 4; ++i) {                                           \
          pk[i] = f2bf(aP0[i] + b0[i]); pk[4 + i] = f2bf(aQ0[i] + b1[i]);       \
        }                                                                       \
        *(short8b*)(gi_all + m * G_DIM + g0) = pk;                              \
      }                                                                         \
      m = m0 + 16 + lr;                                                         \
      if (m < N_NODES) {                                                        \
        short8b pk;                                                             \
        _Pragma("unroll")                                                       \
        for (int i = 0; i < 4; ++i) {                                           \
          pk[i] = f2bf(aP1[i] + b0[i]); pk[4 + i] = f2bf(aQ1[i] + b1[i]);       \
        }                                                                       \
        *(short8b*)(gi_all + m * G_DIM + g0) = pk;                              \
      }                                                                         \
    }                                                                           \
  }

__global__ __launch_bounds__(256) void k_gemm_x(
    const unsigned short* __restrict__ xb,
    const unsigned short* __restrict__ wib,
    const float* __restrict__ b_ih,
    unsigned short* __restrict__ gi_all) {
    const int tid = threadIdx.x;
    const int wv = tid >> 6, lane = tid & 63;
    const int lr = lane & 15, kg = lane >> 4;
    const long m0 = (long)blockIdx.x * 128 + wv * 32;

    short8b A[2][8];
#pragma unroll
    for (int ms = 0; ms < 2; ++ms) {
        long r = m0 + ms * 16 + lr;
        if (r > N_NODES - 1) r = N_NODES - 1;
        const unsigned short* xp = xb + r * F_DIM + kg * 8;
#pragma unroll
        for (int ks = 0; ks < 8; ++ks)
            A[ms][ks] = *(const short8b*)(xp + ks * 32);
    }

    const int gp_off = (lr >> 2) * 8 + (lr & 3);
    const f32x4 zf = {0.f, 0.f, 0.f, 0.f};

    short8b Be[16], Bo[16];
    LOADB(Be, 0);
#pragma unroll
    for (int ph = 0; ph < 12; ++ph) {
        GXSTEP(Be, Bo, 2 * ph);
        GXSTEP(Bo, Be, 2 * ph + 1);
    }
}

// ---------------------------------------------------------------------------
// One depth layer: gather h_prev = mean(children h) -> LDS (bf16), K=256 GEMM
// vs whb with register-double-buffered B per gate chunk, fused GRU epilogue.
// Tile = 32 nodes, 512 threads (8 waves x 32 gate cols each). No atomics.
// ---------------------------------------------------------------------------
#define LOADW(Bdst, c_)                                                         \
  {                                                                             \
    _Pragma("unroll")                                                           \
    for (int ns = 0; ns < 2; ++ns) {                                            \
      const unsigned short* bp_ = whb +                                         \
          (size_t)((c_) * 256 + cb + ns * 16 + lr) * H_DIM + kg * 8;            \
      _Pragma("unroll")                                                         \
      for (int ks = 0; ks < 8; ++ks)                                            \
        Bdst[ns * 8 + ks] = *(const short8b*)(bp_ + ks * 32);                   \
    }                                                                           \
  }

#define MMAC(c_, Bc)                                                            \
  _Pragma("unroll")                                                             \
  for (int ks = 0; ks < 8; ++ks)                                                \
    _Pragma("unroll")                                                           \
    for (int ns = 0; ns < 2; ++ns)                                              \
      _Pragma("unroll")                                                         \
      for (int ms = 0; ms < 2; ++ms)                                            \
        acc[c_][ms][ns] = __builtin_amdgcn_mfma_f32_16x16x32_bf16(              \
            A_[ms][ks], Bc[ns * 8 + ks], acc[c_][ms][ns], 0, 0, 0);

__global__ __launch_bounds__(512) void k_layer(
    const int* __restrict__ layer_nodes,
    const int* __restrict__ child_idx,
    const int* __restrict__ child_cnt,
    const int* __restrict__ Mdev,
    const int* __restrict__ layer_cnt,
    const unsigned short* __restrict__ whb,
    const unsigned short* __restrict__ gi_all,
    const float* __restrict__ b_hh,
    unsigned short* __restrict__ h_all,
    float* __restrict__ out,
    int d, int C) {
    __shared__ unsigned short Ab[32][274];  // scaled h_prev bf16 (odd-dword pad)
    __shared__ int Nd[32];

    const int cntd = layer_cnt[d];
    if (cntd == 0) return;
    const int M = Mdev[0];
    const int ntiles = (cntd + 31) >> 5;
    const long pbase = (long)d * M;

    const int tid = threadIdx.x;
    const int wv = tid >> 6, lane = tid & 63;
    const int lr = lane & 15, kg = lane >> 4;
    const int cb = wv * 32;                 // this wave's 32 gate cols per chunk

    float bh[3][2];
#pragma unroll
    for (int c = 0; c < 3; ++c)
#pragma unroll
        for (int ns = 0; ns < 2; ++ns)
            bh[c][ns] = b_hh[c * 256 + cb + ns * 16 + lr];

    const int srow = tid >> 4;              // 0..31 staging row (16 thr/row)
    const int sc16 = (tid & 15) * 16;       // 16 bf16 cols per thread

    for (int tile = blockIdx.x; tile < ntiles; tile += gridDim.x) {
        __syncthreads();   // previous tile's Ab reads (MFMA + hp) done
        // ---- gather staging: h_prev = mean(children h), bf16 into LDS ----
        {
            int idx = tile * 32 + srow;
            int node = (idx < cntd) ? layer_nodes[pbase + idx] : -1;
            if ((tid & 15) == 0) Nd[srow] = node;
            float sum[16];
#pragma unroll
            for (int i = 0; i < 16; ++i) sum[i] = 0.f;
            if (node >= 0) {
                int cc = child_cnt[pbase + idx];
                const int* ch = child_idx + (size_t)(pbase + idx) * C;
                for (int c = 0; c < cc; ++c) {
                    int kid = ch[c];
                    const unsigned short* hr = h_all + (size_t)kid * H_DIM + sc16;
                    short8b v0 = *(const short8b*)hr;
                    short8b v1 = *(const short8b*)(hr + 8);
#pragma unroll
                    for (int i = 0; i < 8; ++i) {
                        sum[i]     += bf2f((unsigned short)v0[i]);
                        sum[8 + i] += bf2f((unsigned short)v1[i]);
                    }
                }
                float inv = 1.0f / (float)(cc > 0 ? cc : 1);
#pragma unroll
                for (int i = 0; i < 16; ++i) sum[i] *= inv;
            }
            short8b p0, p1;
#pragma unroll
            for (int i = 0; i < 8; ++i) { p0[i] = f2bf(sum[i]); p1[i] = f2bf(sum[8 + i]); }
            *(short8b*)&Ab[srow][sc16] = p0;
            *(short8b*)&Ab[srow][sc16 + 8] = p1;
        }
        __syncthreads();

        // ---- early-issue gi loads (land under the MFMA phase) ----
        int nds[2][4];
        unsigned short g_r[2][4][2], g_z[2][4][2], g_n[2][4][2];
#pragma unroll
        for (int ms = 0; ms < 2; ++ms)
#pragma unroll
            for (int i = 0; i < 4; ++i) {
                int nd = Nd[ms * 16 + kg * 4 + i];
                nds[ms][i] = nd;
                const unsigned short* gp =
                    gi_all + (size_t)(nd >= 0 ? nd : 0) * G_DIM;
#pragma unroll
                for (int ns = 0; ns < 2; ++ns) {
                    int k = cb + ns * 16 + lr;
                    g_r[ms][i][ns] = gp[k];
                    g_z[ms][i][ns] = gp[256 + k];
                    g_n[ms][i][ns] = gp[512 + k];
                }
            }

        // ---- A fragments from LDS ----
        short8b A_[2][8];
#pragma unroll
        for (int ms = 0; ms < 2; ++ms)
#pragma unroll
            for (int ks = 0; ks < 8; ++ks)
                A_[ms][ks] = *(const short8b*)&Ab[ms * 16 + lr][ks * 32 + kg * 8];

        // ---- GEMM with double-buffered B (per gate chunk) ----
        const f32x4 zf = {0.f, 0.f, 0.f, 0.f};
        f32x4 acc[3][2][2];
#pragma unroll
        for (int c = 0; c < 3; ++c)
#pragma unroll
            for (int ms = 0; ms < 2; ++ms)
#pragma unroll
                for (int ns = 0; ns < 2; ++ns) acc[c][ms][ns] = zf;

        short8b Be[16], Bo[16];
        LOADW(Be, 0);
        LOADW(Bo, 1);
        MMAC(0, Be);
        LOADW(Be, 2);
        MMAC(1, Bo);
        MMAC(2, Be);

        // ---- fused GRU epilogue ----
#pragma unroll
        for (int ms = 0; ms < 2; ++ms)
#pragma unroll
            for (int ns = 0; ns < 2; ++ns) {
                int k = cb + ns * 16 + lr;
#pragma unroll
                for (int i = 0; i < 4; ++i) {
                    int nd = nds[ms][i];
                    if (nd < 0) continue;
                    int rl = ms * 16 + kg * 4 + i;
                    float hp = bf2f(Ab[rl][k]);
                    float xr = bf2f(g_r[ms][i][ns]) + acc[0][ms][ns][i] + bh[0][ns];
                    float xz = bf2f(g_z[ms][i][ns]) + acc[1][ms][ns][i] + bh[1][ns];
                    float r = 1.0f / (1.0f + expf(-xr));
                    float z = 1.0f / (1.0f + expf(-xz));
                    float n = tanhf(bf2f(g_n[ms][i][ns]) + r * (acc[2][ms][ns][i] + bh[2][ns]));
                    float h = (1.0f - z) * n + z * hp;
                    if (d == 0) {
                        out[(size_t)(nd / S_NODES) * H_DIM + k] = h;
                    } else {
                        h_all[(size_t)nd * H_DIM + k] = f2bf(h);
                    }
                }
            }
    }
}

// ---------------------------------------------------------------------------
extern "C" void kernel_launch(void* const* d_in, const int* in_sizes, int n_in,
                              void* d_out, int out_size, void* d_ws, size_t ws_size,
                              hipStream_t stream) {
    const float* inputs = (const float*)d_in[0];
    const float* w_ih   = (const float*)d_in[1];
    const float* w_hh   = (const float*)d_in[2];
    const float* b_ih   = (const float*)d_in[3];
    const float* b_hh   = (const float*)d_in[4];
    const int* layer_nodes = (const int*)d_in[5];
    const int* child_idx   = (const int*)d_in[6];
    const int* child_cnt   = (const int*)d_in[7];

    const int LM = in_sizes[5];
    const int C  = in_sizes[6] / in_sizes[5];

    char* w = (char*)d_ws;
    size_t o = 0;
    auto alloc = [&](size_t bytes) {
        void* p = w + o;
        o += (bytes + 255) & ~(size_t)255;
        return p;
    };
    unsigned short* wib    = (unsigned short*)alloc((size_t)G_DIM * F_DIM * 2);
    unsigned short* whb    = (unsigned short*)alloc((size_t)G_DIM * H_DIM * 2);
    unsigned short* xb     = (unsigned short*)alloc((size_t)N_NODES * F_DIM * 2);
    unsigned short* h_all  = (unsigned short*)alloc((size_t)N_NODES * H_DIM * 2);
    unsigned short* gi_all = (unsigned short*)alloc((size_t)N_NODES * G_DIM * 2);
    int*            Mdev      = (int*)alloc(4);
    int*            layer_cnt = (int*)alloc(D_MAX * 4);
    (void)ws_size;

    hipMemsetAsync(Mdev, 0x7F, 4, stream);                 // 0x7F7F7F7F > LM
    hipMemsetAsync(layer_cnt, 0, D_MAX * 4, stream);

    k_zero<<<2048, 256, 0, stream>>>((float4*)h_all, N_NODES * H_DIM * 2 / 16);
    k_convx<<<2048, 256, 0, stream>>>(inputs, xb, N_NODES * F_DIM / 8);
    k_findM<<<256, 256, 0, stream>>>(layer_nodes, LM, Mdev);
    k_hist<<<256, 256, 0, stream>>>(layer_nodes, Mdev, layer_cnt, LM);
    k_convw<<<(G_DIM * F_DIM + 255) / 256, 256, 0, stream>>>(w_ih, w_hh, wib, whb);

    // One-shot feed-forward GEMM (b_ih folded in)
    k_gemm_x<<<(N_NODES + 127) / 128, 256, 0, stream>>>(xb, wib, b_ih, gi_all);

    // Depth layers, deepest first (empty layers exit immediately)
    for (int d = D_MAX - 1; d >= 0; --d)
        k_layer<<<512, 512, 0, stream>>>(layer_nodes, child_idx, child_cnt,
                                         Mdev, layer_cnt, whb, gi_all, b_hh,
                                         h_all, (float*)d_out, d, C);
}

// Round 8
// 1130.309 us; speedup vs baseline: 1.9254x; 1.1877x over previous
//
#include <hip/hip_runtime.h>
#include <hip/hip_bf16.h>
#include <math.h>

#define N_NODES 200000
#define T_TREES 2000
#define S_NODES 100
#define F_DIM 256
#define H_DIM 256
#define G_DIM 768   // 3*H
#define D_MAX 28    // upper bound on depth layers (actual ~16)

typedef __attribute__((ext_vector_type(8))) short short8b;   // 8 bf16 = 4 VGPR
typedef __attribute__((ext_vector_type(4))) float f32x4;

static __device__ __forceinline__ unsigned short f2bf(float x) {
    union { __hip_bfloat16 h; unsigned short u; } cv;
    cv.h = __float2bfloat16(x);
    return cv.u;
}
static __device__ __forceinline__ float bf2f(unsigned short u) {
    return __uint_as_float(((unsigned)u) << 16);
}

// ---------------------------------------------------------------------------
__global__ void k_zero(float4* __restrict__ p, int n4) {
    float4 z = make_float4(0.f, 0.f, 0.f, 0.f);
    for (int i = blockIdx.x * blockDim.x + threadIdx.x; i < n4;
         i += gridDim.x * blockDim.x)
        p[i] = z;
}

// x (fp32) -> bf16, 8 elems/thread
__global__ void k_convx(const float* __restrict__ x, unsigned short* __restrict__ xb,
                        int n8) {
    for (int i = blockIdx.x * blockDim.x + threadIdx.x; i < n8;
         i += gridDim.x * blockDim.x) {
        const float4* px = (const float4*)(x + (size_t)i * 8);
        float4 u = px[0], v = px[1];
        short8b t;
        t[0] = f2bf(u.x); t[1] = f2bf(u.y); t[2] = f2bf(u.z); t[3] = f2bf(u.w);
        t[4] = f2bf(v.x); t[5] = f2bf(v.y); t[6] = f2bf(v.z); t[7] = f2bf(v.w);
        *(short8b*)(xb + (size_t)i * 8) = t;
    }
}

// M = min{ p >= T : layer_nodes[p] < N } (layer 0 is exactly the T roots)
__global__ void k_findM(const int* __restrict__ ln, int LM, int* __restrict__ Mdev) {
    int local = 0x7F7F7F7F;
    for (int p = T_TREES + blockIdx.x * blockDim.x + threadIdx.x; p < LM;
         p += gridDim.x * blockDim.x)
        if (ln[p] < N_NODES && p < local) local = p;
#pragma unroll
    for (int off = 32; off; off >>= 1) {
        int o = __shfl_down(local, off);
        if (o < local) local = o;
    }
    __shared__ int wmin[4];
    if ((threadIdx.x & 63) == 0) wmin[threadIdx.x >> 6] = local;
    __syncthreads();
    if (threadIdx.x == 0) {
        int m = wmin[0];
        for (int i = 1; i < 4; ++i) if (wmin[i] < m) m = wmin[i];
        if (m < 0x7F7F7F7F) atomicMin(Mdev, m);
    }
}

// layer_cnt[d] = #valid nodes in layer d (valid entries are a row prefix)
__global__ void k_hist(const int* __restrict__ ln, const int* __restrict__ Mdev,
                       int* __restrict__ layer_cnt, int LM) {
    __shared__ int h[D_MAX];
    if (threadIdx.x < D_MAX) h[threadIdx.x] = 0;
    __syncthreads();
    const int M = Mdev[0];
    for (int p = blockIdx.x * blockDim.x + threadIdx.x; p < LM;
         p += gridDim.x * blockDim.x)
        if (ln[p] < N_NODES) {
            int d = p / M;
            if (d < D_MAX) atomicAdd(&h[d], 1);
        }
    __syncthreads();
    if (threadIdx.x < D_MAX && h[threadIdx.x])
        atomicAdd(&layer_cnt[threadIdx.x], h[threadIdx.x]);
}

// Weights fp32 -> bf16 (row-major [g][k])
__global__ void k_convw(const float* __restrict__ wi, const float* __restrict__ wh,
                        unsigned short* __restrict__ wib, unsigned short* __restrict__ whb) {
    int i = blockIdx.x * blockDim.x + threadIdx.x;
    if (i < G_DIM * F_DIM) {
        wib[i] = f2bf(wi[i]);
        whb[i] = f2bf(wh[i]);
    }
}

// ---------------------------------------------------------------------------
// One-shot GEMM: gi_all[m][g] = (sum_k xb[m][k] * w_ih[g][k]) + b_ih[g]  (bf16)
// B staged in LDS (64-gate tiles, double-buffered, shared by 4 waves).
// T14 split: issue next-tile loads -> compute current -> barrier -> ds_write.
// LDS layout swizzled: 64B-slot index = ks ^ ((row>>3)&1)  => b128 reads 2-way.
// ---------------------------------------------------------------------------
__global__ __launch_bounds__(256) void k_gemm_x(
    const unsigned short* __restrict__ xb,
    const unsigned short* __restrict__ wib,
    const float* __restrict__ b_ih,
    unsigned short* __restrict__ gi_all) {
    __shared__ unsigned short Bs[2][64][256];

    const int tid = threadIdx.x;
    const int wv = tid >> 6, lane = tid & 63;
    const int lr = lane & 15, kg = lane >> 4;
    const long m0 = (long)blockIdx.x * 128 + wv * 32;

    // A fragments resident (reused for all 12 gate tiles)
    short8b A[2][8];
#pragma unroll
    for (int ms = 0; ms < 2; ++ms) {
        long r = m0 + ms * 16 + lr;
        if (r > N_NODES - 1) r = N_NODES - 1;
        const unsigned short* xp = xb + r * F_DIM + kg * 8;
#pragma unroll
        for (int ks = 0; ks < 8; ++ks)
            A[ms][ks] = *(const short8b*)(xp + ks * 32);
    }

    // staging mapping: thread stages row sr (16 rows/wave), 4 chunks of 16 ush
    const int sr = tid >> 2, sp = tid & 3;
    const int psr = (sr >> 3) & 1;                 // row's swizzle bit
    // read mapping: permuted rows for contiguous-g output
    const int gp_off = (lr >> 2) * 8 + (lr & 3);   // in {0..3,8..11,16..19,24..27}
    const int prow = (gp_off >> 3) & 1;            // same for gp_off+4

    short8b st[8];
    // ---- prologue: stage tile 0 ----
    {
        const unsigned short* src = wib + (size_t)sr * F_DIM;
#pragma unroll
        for (int q = 0; q < 4; ++q) {
            int c = sp * 16 + q * 64;
            st[2 * q]     = *(const short8b*)(src + c);
            st[2 * q + 1] = *(const short8b*)(src + c + 8);
        }
#pragma unroll
        for (int q = 0; q < 4; ++q) {
            int slot = (sp >> 1) + 2 * q;
            int pc = ((slot ^ psr) << 5) + (sp & 1) * 16;
            *(short8b*)&Bs[0][sr][pc]     = st[2 * q];
            *(short8b*)&Bs[0][sr][pc + 8] = st[2 * q + 1];
        }
    }
    __syncthreads();

    const f32x4 zf = {0.f, 0.f, 0.f, 0.f};

    for (int nt = 0; nt < 12; ++nt) {
        const int cur = nt & 1;
        // ---- issue next tile's global loads (land under MFMA) ----
        if (nt < 11) {
            const unsigned short* src = wib + (size_t)((nt + 1) * 64 + sr) * F_DIM;
#pragma unroll
            for (int q = 0; q < 4; ++q) {
                int c = sp * 16 + q * 64;
                st[2 * q]     = *(const short8b*)(src + c);
                st[2 * q + 1] = *(const short8b*)(src + c + 8);
            }
        }
        // ---- compute from Bs[cur] ----
#pragma unroll
        for (int nsp = 0; nsp < 2; ++nsp) {
            f32x4 aP0 = zf, aQ0 = zf, aP1 = zf, aQ1 = zf;
            const int rP = nsp * 32 + gp_off;
#pragma unroll
            for (int ks = 0; ks < 8; ++ks) {
                const int pc = ((ks ^ prow) << 5) + kg * 8;
                short8b BP = *(const short8b*)&Bs[cur][rP][pc];
                short8b BQ = *(const short8b*)&Bs[cur][rP + 4][pc];
                aP0 = __builtin_amdgcn_mfma_f32_16x16x32_bf16(BP, A[0][ks], aP0, 0, 0, 0);
                aQ0 = __builtin_amdgcn_mfma_f32_16x16x32_bf16(BQ, A[0][ks], aQ0, 0, 0, 0);
                aP1 = __builtin_amdgcn_mfma_f32_16x16x32_bf16(BP, A[1][ks], aP1, 0, 0, 0);
                aQ1 = __builtin_amdgcn_mfma_f32_16x16x32_bf16(BQ, A[1][ks], aQ1, 0, 0, 0);
            }
            const int g0 = nt * 64 + nsp * 32 + kg * 8;
            f32x4 b0 = *(const f32x4*)(b_ih + g0);
            f32x4 b1 = *(const f32x4*)(b_ih + g0 + 4);
            long m = m0 + lr;
            if (m < N_NODES) {
                short8b pk;
#pragma unroll
                for (int i = 0; i < 4; ++i) {
                    pk[i]     = f2bf(aP0[i] + b0[i]);
                    pk[4 + i] = f2bf(aQ0[i] + b1[i]);
                }
                *(short8b*)(gi_all + m * G_DIM + g0) = pk;
            }
            m = m0 + 16 + lr;
            if (m < N_NODES) {
                short8b pk;
#pragma unroll
                for (int i = 0; i < 4; ++i) {
                    pk[i]     = f2bf(aP1[i] + b0[i]);
                    pk[4 + i] = f2bf(aQ1[i] + b1[i]);
                }
                *(short8b*)(gi_all + m * G_DIM + g0) = pk;
            }
        }
        // ---- write staged tile into the other buffer ----
        if (nt < 11) {
            __syncthreads();
#pragma unroll
            for (int q = 0; q < 4; ++q) {
                int slot = (sp >> 1) + 2 * q;
                int pc = ((slot ^ psr) << 5) + (sp & 1) * 16;
                *(short8b*)&Bs[cur ^ 1][sr][pc]     = st[2 * q];
                *(short8b*)&Bs[cur ^ 1][sr][pc + 8] = st[2 * q + 1];
            }
            __syncthreads();
        }
    }
}

// ---------------------------------------------------------------------------
// One depth layer: gather h_prev = mean(children h) -> swizzled LDS (bf16),
// K=256 GEMM vs whb (L2-hot), fused GRU epilogue. 256 thr / 4 waves; tile =
// 32 nodes x 128 gate-cols (2 col-groups per tile). acc = 48 VGPR;
// A-frags on-demand from LDS. No atomics.
// ---------------------------------------------------------------------------
__global__ __launch_bounds__(256) void k_layer(
    const int* __restrict__ layer_nodes,
    const int* __restrict__ child_idx,
    const int* __restrict__ child_cnt,
    const int* __restrict__ Mdev,
    const int* __restrict__ layer_cnt,
    const unsigned short* __restrict__ whb,
    const unsigned short* __restrict__ gi_all,
    const float* __restrict__ b_hh,
    unsigned short* __restrict__ h_all,
    float* __restrict__ out,
    int d, int C) {
    __shared__ unsigned short Ab[32][256];   // swizzled: slot = (col>>5)^((row>>3)&1)
    __shared__ int Nd[32];

    const int cntd = layer_cnt[d];
    if (cntd == 0) return;
    const int M = Mdev[0];
    const int ntiles = (cntd + 31) >> 5;
    const long pbase = (long)d * M;

    const int tid = threadIdx.x;
    const int wv = tid >> 6, lane = tid & 63;
    const int lr = lane & 15, kg = lane >> 4;
    const int srow = tid >> 3, sc = tid & 7;
    const int psr = (srow >> 3) & 1;
    const int p0 = (lr >> 3) & 1;            // A-read swizzle bit (rows lr, 16+lr)
    const int prl = (kg >> 1) & 1;           // hp-read swizzle bit

    for (int w = blockIdx.x; w < ntiles * 2; w += gridDim.x) {
        const int tile = w >> 1, cg = w & 1;
        const int cb = cg * 128 + wv * 32;   // col base within each 256-chunk

        __syncthreads();   // previous work-item's Ab reads done
        // ---- gather staging: h_prev = mean(children h), swizzled bf16 LDS ----
        {
            int idx = tile * 32 + srow;
            int node = (idx < cntd) ? layer_nodes[pbase + idx] : -1;
            if (sc == 0) Nd[srow] = node;
            int cc = 0;
            const int* ch = nullptr;
            if (node >= 0) {
                cc = child_cnt[pbase + idx];
                ch = child_idx + (size_t)(pbase + idx) * C;
            }
            float inv = 1.0f / (float)(cc > 0 ? cc : 1);
#pragma unroll
            for (int pass = 0; pass < 2; ++pass) {
                const int col = sc * 16 + pass * 128;
                float sum[16];
#pragma unroll
                for (int i = 0; i < 16; ++i) sum[i] = 0.f;
                for (int c = 0; c < cc; ++c) {
                    int kid = ch[c];
                    const unsigned short* hr = h_all + (size_t)kid * H_DIM + col;
                    short8b v0 = *(const short8b*)hr;
                    short8b v1 = *(const short8b*)(hr + 8);
#pragma unroll
                    for (int i = 0; i < 8; ++i) {
                        sum[i]     += bf2f((unsigned short)v0[i]);
                        sum[8 + i] += bf2f((unsigned short)v1[i]);
                    }
                }
                short8b q0, q1;
#pragma unroll
                for (int i = 0; i < 8; ++i) {
                    q0[i] = f2bf(sum[i] * inv);
                    q1[i] = f2bf(sum[8 + i] * inv);
                }
                int slot = (sc >> 1) + pass * 4;
                int pc = ((slot ^ psr) << 5) + (sc & 1) * 16;
                *(short8b*)&Ab[srow][pc]     = q0;
                *(short8b*)&Ab[srow][pc + 8] = q1;
            }
        }
        __syncthreads();

        // ---- GEMM: acc[c][ms][ns] = h_prev @ w_hh^T (A on-demand from LDS) ----
        const f32x4 zf = {0.f, 0.f, 0.f, 0.f};
        f32x4 acc[3][2][2];
#pragma unroll
        for (int c = 0; c < 3; ++c)
#pragma unroll
            for (int ms = 0; ms < 2; ++ms)
#pragma unroll
                for (int ns = 0; ns < 2; ++ns) acc[c][ms][ns] = zf;

#pragma unroll
        for (int ks = 0; ks < 8; ++ks) {
            const int pc = ((ks ^ p0) << 5) + kg * 8;
            short8b A0 = *(const short8b*)&Ab[lr][pc];
            short8b A1 = *(const short8b*)&Ab[16 + lr][pc];
#pragma unroll
            for (int c = 0; c < 3; ++c)
#pragma unroll
                for (int ns = 0; ns < 2; ++ns) {
                    short8b B = *(const short8b*)(whb
                        + (size_t)(c * 256 + cb + ns * 16 + lr) * H_DIM
                        + ks * 32 + kg * 8);
                    acc[c][0][ns] = __builtin_amdgcn_mfma_f32_16x16x32_bf16(
                        A0, B, acc[c][0][ns], 0, 0, 0);
                    acc[c][1][ns] = __builtin_amdgcn_mfma_f32_16x16x32_bf16(
                        A1, B, acc[c][1][ns], 0, 0, 0);
                }
        }

        // ---- fused GRU epilogue ----
#pragma unroll
        for (int ms = 0; ms < 2; ++ms)
#pragma unroll
            for (int i = 0; i < 4; ++i) {
                const int rl = ms * 16 + kg * 4 + i;
                const int nd = Nd[rl];
                if (nd < 0) continue;
                const unsigned short* gp = gi_all + (size_t)nd * G_DIM;
#pragma unroll
                for (int ns = 0; ns < 2; ++ns) {
                    const int k = cb + ns * 16 + lr;
                    const int hp_pc = (((k >> 5) ^ prl) << 5) + (k & 31);
                    float hp = bf2f(Ab[rl][hp_pc]);
                    float xr = bf2f(gp[k])       + acc[0][ms][ns][i] + b_hh[k];
                    float xz = bf2f(gp[256 + k]) + acc[1][ms][ns][i] + b_hh[256 + k];
                    float r = 1.0f / (1.0f + expf(-xr));
                    float z = 1.0f / (1.0f + expf(-xz));
                    float n = tanhf(bf2f(gp[512 + k]) +
                                    r * (acc[2][ms][ns][i] + b_hh[512 + k]));
                    float h = (1.0f - z) * n + z * hp;
                    if (d == 0) {
                        out[(size_t)(nd / S_NODES) * H_DIM + k] = h;
                    } else {
                        h_all[(size_t)nd * H_DIM + k] = f2bf(h);
                    }
                }
            }
    }
}

// ---------------------------------------------------------------------------
extern "C" void kernel_launch(void* const* d_in, const int* in_sizes, int n_in,
                              void* d_out, int out_size, void* d_ws, size_t ws_size,
                              hipStream_t stream) {
    const float* inputs = (const float*)d_in[0];
    const float* w_ih   = (const float*)d_in[1];
    const float* w_hh   = (const float*)d_in[2];
    const float* b_ih   = (const float*)d_in[3];
    const float* b_hh   = (const float*)d_in[4];
    const int* layer_nodes = (const int*)d_in[5];
    const int* child_idx   = (const int*)d_in[6];
    const int* child_cnt   = (const int*)d_in[7];

    const int LM = in_sizes[5];
    const int C  = in_sizes[6] / in_sizes[5];

    char* w = (char*)d_ws;
    size_t o = 0;
    auto alloc = [&](size_t bytes) {
        void* p = w + o;
        o += (bytes + 255) & ~(size_t)255;
        return p;
    };
    unsigned short* wib    = (unsigned short*)alloc((size_t)G_DIM * F_DIM * 2);
    unsigned short* whb    = (unsigned short*)alloc((size_t)G_DIM * H_DIM * 2);
    unsigned short* xb     = (unsigned short*)alloc((size_t)N_NODES * F_DIM * 2);
    unsigned short* h_all  = (unsigned short*)alloc((size_t)N_NODES * H_DIM * 2);
    unsigned short* gi_all = (unsigned short*)alloc((size_t)N_NODES * G_DIM * 2);
    int*            Mdev      = (int*)alloc(4);
    int*            layer_cnt = (int*)alloc(D_MAX * 4);
    (void)ws_size;

    hipMemsetAsync(Mdev, 0x7F, 4, stream);                 // 0x7F7F7F7F > LM
    hipMemsetAsync(layer_cnt, 0, D_MAX * 4, stream);

    k_zero<<<2048, 256, 0, stream>>>((float4*)h_all, N_NODES * H_DIM * 2 / 16);
    k_convx<<<2048, 256, 0, stream>>>(inputs, xb, N_NODES * F_DIM / 8);
    k_findM<<<256, 256, 0, stream>>>(layer_nodes, LM, Mdev);
    k_hist<<<256, 256, 0, stream>>>(layer_nodes, Mdev, layer_cnt, LM);
    k_convw<<<(G_DIM * F_DIM + 255) / 256, 256, 0, stream>>>(w_ih, w_hh, wib, whb);

    // One-shot feed-forward GEMM (b_ih folded in)
    k_gemm_x<<<(N_NODES + 127) / 128, 256, 0, stream>>>(xb, wib, b_ih, gi_all);

    // Depth layers, deepest first (empty layers exit immediately)
    for (int d = D_MAX - 1; d >= 0; --d)
        k_layer<<<1024, 256, 0, stream>>>(layer_nodes, child_idx, child_cnt,
                                          Mdev, layer_cnt, whb, gi_all, b_hh,
                                          h_all, (float*)d_out, d, C);
}